// Round 7
// baseline (441.782 us; speedup 1.0000x reference)
//
#include <hip/hip_runtime.h>
#include <math.h>

// Problem constants (from reference): B=4, Cin=64, H=W=160, K=3, pad=1, stride=1, Cout=64
#define B_   4
#define CIN  64
#define H_   160
#define W_   160
#define COUT 64
#define OFFC 27            // DG*3*K*K = 27 offset-conv output channels
#define HW_  (H_ * W_)     // 25600
#define NPIX (B_ * HW_)    // 102400

#define TILE_P 128         // pixels per k_dcn block (128 | HW_)
#define VPITCH 130         // vals row pitch: 2-way-free banks (130%32=2), 8B-aligned float2 rows

// Workspace (floats):
//   Tier A (ws >= 37.4 MB): x_nhwc[NPIX*64] | om[NPIX*27] | wT[576*64]
//   Tier B (ws >= 11.2 MB):                   om[NPIX*27] | wT[576*64]  (NCHW direct gather)

// ---------------------------------------------------------------------------
// Kernel 0a: NCHW -> NHWC transpose of the input via LDS tiles.
// ---------------------------------------------------------------------------
__global__ __launch_bounds__(256) void k_transpose_nhwc(const float* __restrict__ in,
                                                        float* __restrict__ out) {
    __shared__ float tile[CIN][33]; // +1 pad: conflict-free transposed reads
    int blk = blockIdx.x;           // b*H*5 + y*5 + wc
    int wc  = blk % 5;
    int by  = blk / 5;
    int y   = by % H_;
    int b   = by / H_;
    int w0  = wc * 32;
    int t   = threadIdx.x;

    int wi = t & 31, ch = t >> 5;   // ch: 0..7
#pragma unroll
    for (int r = 0; r < 8; ++r) {
        int c = r * 8 + ch;
        tile[c][wi] = in[((b * CIN + c) * H_ + y) * W_ + w0 + wi]; // coalesced in w
    }
    __syncthreads();
    int c2 = t & 63, wj = t >> 6;   // wj: 0..3
#pragma unroll
    for (int r = 0; r < 8; ++r) {
        int wi2 = r * 4 + wj;
        out[((b * H_ + y) * W_ + w0 + wi2) * CIN + c2] = tile[c2][wi2]; // coalesced in c
    }
}

// ---------------------------------------------------------------------------
// Kernel 0b: w_dcn (Cout,Cin,3,3) -> wT[(k*64 + c)*64 + co]
// ---------------------------------------------------------------------------
__global__ void k_transpose_w(const float* __restrict__ w, float* __restrict__ wT) {
    int i  = blockIdx.x * 256 + threadIdx.x;
    int co = i & 63;
    int kc = i >> 6;
    int c  = kc & 63;
    int k  = kc >> 6;
    wT[i] = w[(co * CIN + c) * 9 + k];
}

// ---------------------------------------------------------------------------
// Kernel A: offset conv (Cin=64 -> 27ch, 3x3, pad 1). One thread per pixel.
// Clamped indices + validity hoisted out of the c-loop (c-invariant) ->
// branch-free inner loop: 9 plain loads + 9 mul + 243 FMA per c.
// Output om stored NHWC: om[pixel*27 + o].
// ---------------------------------------------------------------------------
__global__ __launch_bounds__(256) void k_offconv(const float* __restrict__ in,
                                                 const float* __restrict__ wo,
                                                 const float* __restrict__ bo,
                                                 float* __restrict__ om) {
    int bid = (int)blockIdx.x;
    int blk = (bid & 7) * ((NPIX / 256) / 8) + (bid >> 3); // XCD swizzle (400%8==0)
    int p   = blk * 256 + threadIdx.x;                     // 0..NPIX-1
    int b   = p / HW_;
    int rem = p - b * HW_;
    int y   = rem / W_;
    int x   = rem - y * W_;

    // c-invariant per-tap offsets + validity
    int   off[9];
    float valid[9];
#pragma unroll
    for (int di = 0; di < 3; ++di) {
        int yy = y + di - 1;
        int yc = min(max(yy, 0), H_ - 1);
        bool yok = (yy >= 0) & (yy < H_);
#pragma unroll
        for (int dj = 0; dj < 3; ++dj) {
            int xx = x + dj - 1;
            int xc = min(max(xx, 0), W_ - 1);
            bool ok = yok & (xx >= 0) & (xx < W_);
            off[di * 3 + dj]   = yc * W_ + xc;
            valid[di * 3 + dj] = ok ? 1.f : 0.f;
        }
    }

    float acc[OFFC];
#pragma unroll
    for (int o = 0; o < OFFC; ++o) acc[o] = bo[o];

    const float* inb = in + (size_t)b * CIN * HW_;
    for (int c = 0; c < CIN; ++c) {
        float v[9];
#pragma unroll
        for (int tp = 0; tp < 9; ++tp)
            v[tp] = inb[c * HW_ + off[tp]] * valid[tp];
#pragma unroll
        for (int o = 0; o < OFFC; ++o) {
#pragma unroll
            for (int tp = 0; tp < 9; ++tp)
                acc[o] += v[tp] * wo[o * 576 + c * 9 + tp];
        }
    }
    float* omp = om + (size_t)p * OFFC;
#pragma unroll
    for (int o = 0; o < OFFC; ++o) omp[o] = acc[o];
}

// ---------------------------------------------------------------------------
// Kernel B: deformable sampling + K-chunked register-tiled GEMM.
// Block = 256 threads (4 waves), TILE_P=128 contiguous pixels, all 64 couts.
// Template NHWC: true  -> gather from x_nhwc (coalesced 256B, Tier A)
//                false -> gather from NCHW input directly (Tier B fallback;
//                         per-lane-own-line, L2-served, correct but slower).
// Per tap k:
//   setup: threads t<128 build sk[pix][8] = {4 validity-folded bilinear wts,
//          4 pre-clamped offsets} (4 KB LDS).
//   stage: vals[c][pix] (64 x VPITCH): branch-free gathers; LDS 2-way (free).
//   compute: wave w owns couts [16w,16w+16) (readfirstlane -> uniform =>
//          weight loads scalarize to s_load). Thread = 2 pix x 16 couts,
//          32 acc. Per c-step: 1 ds_read_b64 + 16 uniform weights -> 32 FMA.
// LDS 37.3 KB; __launch_bounds__(256,4) pins VGPR<=128 -> 4 blocks/CU.
// Epilogue: transpose via vals -> 256B-coalesced NCHW stores.
// ---------------------------------------------------------------------------
template <bool NHWC>
__global__ __launch_bounds__(256, 4) void k_dcn(const float* __restrict__ xsrc,
                                                const float* __restrict__ om,
                                                const float* __restrict__ wT,
                                                const float* __restrict__ bd,
                                                float* __restrict__ out) {
    __shared__ __align__(16) float sk[TILE_P * 8];        //  4,096 B per-tap setup
    __shared__ __align__(16) float vals[64 * VPITCH];     // 33,280 B (reused as outs)

    int t   = threadIdx.x;
    int bid = (int)blockIdx.x;
    int blk = (bid & 7) * ((NPIX / TILE_P) / 8) + (bid >> 3); // XCD swizzle (800%8==0)
    int p0  = blk * TILE_P;
    int b   = p0 / HW_;          // uniform per block (128 | 25600)
    int rb  = p0 - b * HW_;

    int lane = t & 63;
    int co0  = __builtin_amdgcn_readfirstlane((t >> 6) << 4); // wave-uniform cout base

    float acc[2][16];
#pragma unroll
    for (int j = 0; j < 16; ++j) {
        float bj = bd[co0 + j];
        acc[0][j] = bj;
        acc[1][j] = bj;
    }

    const float* base = xsrc + (size_t)b * CIN * HW_;

    for (int k = 0; k < 9; ++k) {
        __syncthreads(); // prev compute done reading vals; sk free to rewrite

        // ---- per-tap setup (threads 0..127, one pixel each) --------------
        if (t < TILE_P) {
            int pix = t;
            int p   = p0 + pix;
            int rem = rb + pix;
            int y   = rem / W_;
            int x   = rem - y * W_;
            float oy = om[p * 27 + 2 * k];
            float ox = om[p * 27 + 2 * k + 1];
            float mr = om[p * 27 + 18 + k];
            float m  = 1.f / (1.f + expf(-mr));
            int ki = k / 3, kj = k - ki * 3;
            float fy  = (float)(y - 1 + ki) + oy;
            float fx  = (float)(x - 1 + kj) + ox;
            float fy0 = floorf(fy), fx0 = floorf(fx);
            float dy = fy - fy0, dx = fx - fx0;
            int iy = (int)fy0, ix = (int)fx0;
            bool yok0 = (iy >= 0) & (iy < H_);
            bool yok1 = (iy + 1 >= 0) & (iy + 1 < H_);
            bool xok0 = (ix >= 0) & (ix < W_);
            bool xok1 = (ix + 1 >= 0) & (ix + 1 < W_);
            int iyc0 = min(max(iy, 0), H_ - 1);
            int iyc1 = min(max(iy + 1, 0), H_ - 1);
            int ixc0 = min(max(ix, 0), W_ - 1);
            int ixc1 = min(max(ix + 1, 0), W_ - 1);
            const int mul = NHWC ? 64 : 1;
            float4 swt, sof;
            swt.x = (1.f - dy) * (1.f - dx) * m * (float)(yok0 & xok0);
            swt.y = (1.f - dy) * dx         * m * (float)(yok0 & xok1);
            swt.z = dy * (1.f - dx)         * m * (float)(yok1 & xok0);
            swt.w = dy * dx                 * m * (float)(yok1 & xok1);
            sof.x = __int_as_float((iyc0 * W_ + ixc0) * mul);
            sof.y = __int_as_float((iyc0 * W_ + ixc1) * mul);
            sof.z = __int_as_float((iyc1 * W_ + ixc0) * mul);
            sof.w = __int_as_float((iyc1 * W_ + ixc1) * mul);
            *reinterpret_cast<float4*>(sk + pix * 8)     = swt;
            *reinterpret_cast<float4*>(sk + pix * 8 + 4) = sof;
        }
        __syncthreads(); // sk ready

        // ---- stage vals[c][pix] (branch-free gathers) --------------------
        int cbase = NHWC ? (t & 63) : (t & 63) * HW_; // c-term of gather index
#pragma unroll 4
        for (int it = 0; it < 32; ++it) {
            int i   = t + it * 256;
            int c   = i & 63;        // lane-varying (== t&63 every iter)
            int pix = i >> 6;        // wave-uniform
            const float* s = sk + pix * 8;
            float4 sw = *reinterpret_cast<const float4*>(s);
            float4 so = *reinterpret_cast<const float4*>(s + 4);
            float g00 = base[__float_as_int(so.x) + cbase];
            float g01 = base[__float_as_int(so.y) + cbase];
            float g10 = base[__float_as_int(so.z) + cbase];
            float g11 = base[__float_as_int(so.w) + cbase];
            vals[c * VPITCH + pix] = g00 * sw.x + g01 * sw.y + g10 * sw.z + g11 * sw.w;
        }
        __syncthreads(); // vals ready

        // ---- compute: 64 c-steps, 2 pix x 16 couts per thread ------------
        const float* wk = wT + (k * 64) * 64 + co0;
#pragma unroll 4
        for (int c = 0; c < 64; ++c) {
            float2 v = *reinterpret_cast<const float2*>(vals + c * VPITCH + 2 * lane);
            const float* wp = wk + c * 64;   // wave-uniform address -> s_load
            float4 wv0 = *reinterpret_cast<const float4*>(wp);
            float4 wv1 = *reinterpret_cast<const float4*>(wp + 4);
            float4 wv2 = *reinterpret_cast<const float4*>(wp + 8);
            float4 wv3 = *reinterpret_cast<const float4*>(wp + 12);
            float wr[16] = {wv0.x, wv0.y, wv0.z, wv0.w,
                            wv1.x, wv1.y, wv1.z, wv1.w,
                            wv2.x, wv2.y, wv2.z, wv2.w,
                            wv3.x, wv3.y, wv3.z, wv3.w};
#pragma unroll
            for (int j = 0; j < 16; ++j) {
                acc[0][j] += v.x * wr[j];
                acc[1][j] += v.y * wr[j];
            }
        }
    }

    // ---- Epilogue: transpose via LDS -> coalesced NCHW stores ------------
    __syncthreads(); // all compute reads of vals done
#pragma unroll
    for (int j = 0; j < 16; ++j) {
        float2 o2;
        o2.x = acc[0][j];
        o2.y = acc[1][j];
        *reinterpret_cast<float2*>(vals + (co0 + j) * VPITCH + 2 * lane) = o2;
    }
    __syncthreads();
#pragma unroll 4
    for (int it = 0; it < 32; ++it) {
        int i   = t + it * 256;
        int co  = i >> 7;            // 0..63
        int pix = i & 127;           // 64 consecutive per wave-instr -> 256B stores
        out[((size_t)(b * COUT + co)) * HW_ + rb + pix] = vals[co * VPITCH + pix];
    }
}

extern "C" void kernel_launch(void* const* d_in, const int* in_sizes, int n_in,
                              void* d_out, int out_size, void* d_ws, size_t ws_size,
                              hipStream_t stream) {
    const float* input = (const float*)d_in[0]; // (4,64,160,160)
    const float* w_off = (const float*)d_in[1]; // (27,64,3,3)
    const float* b_off = (const float*)d_in[2]; // (27,)
    const float* w_dcn = (const float*)d_in[3]; // (64,64,3,3)
    const float* b_dcn = (const float*)d_in[4]; // (64,)
    float* out = (float*)d_out;                 // (4,64,160,160)

    const size_t XN_F = (size_t)NPIX * CIN;     // 6,553,600 floats
    const size_t OM_F = (size_t)NPIX * OFFC;    // 2,764,800 floats
    const size_t WT_F = 576 * 64;               //    36,864 floats
    const size_t need_full = (XN_F + OM_F + WT_F) * sizeof(float); // ~37.4 MB

    float* ws = (float*)d_ws;
    // ws_size is constant across calls -> this branch is graph-capture-safe
    // and does identical work every launch.
    if (ws_size >= need_full) {
        // Tier A: full pipeline with NHWC-staged input.
        float* x_nhwc = ws;
        float* om     = ws + XN_F;
        float* wT     = om + OM_F;
        k_transpose_nhwc<<<dim3(B_ * H_ * 5), dim3(256), 0, stream>>>(input, x_nhwc);
        k_transpose_w<<<dim3(144), dim3(256), 0, stream>>>(w_dcn, wT);
        k_offconv<<<dim3(NPIX / 256), dim3(256), 0, stream>>>(input, w_off, b_off, om);
        k_dcn<true><<<dim3(NPIX / TILE_P), dim3(256), 0, stream>>>(x_nhwc, om, wT, b_dcn, out);
    } else {
        // Tier B: no NHWC staging; k_dcn gathers NCHW directly (slower, safe).
        float* om = ws;
        float* wT = om + OM_F;
        k_transpose_w<<<dim3(144), dim3(256), 0, stream>>>(w_dcn, wT);
        k_offconv<<<dim3(NPIX / 256), dim3(256), 0, stream>>>(input, w_off, b_off, om);
        k_dcn<false><<<dim3(NPIX / TILE_P), dim3(256), 0, stream>>>(input, om, wT, b_dcn, out);
    }
}

// Round 8
// 328.392 us; speedup vs baseline: 1.3453x; 1.3453x over previous
//
#include <hip/hip_runtime.h>
#include <math.h>

// Problem constants (from reference): B=4, Cin=64, H=W=160, K=3, pad=1, stride=1, Cout=64
#define B_   4
#define CIN  64
#define H_   160
#define W_   160
#define COUT 64
#define OFFC 27            // DG*3*K*K = 27 offset-conv output channels
#define HW_  (H_ * W_)     // 25600
#define NPIX (B_ * HW_)    // 102400

#define TILE_P 128         // pixels per k_dcn block (128 | HW_)
#define VPITCH 130         // vals row pitch (float2-aligned rows; 4-way banking, measured minor)

// Workspace (floats):
//   Tier A (ws >= 37.4 MB): x_nhwc[NPIX*64] | om2[27*NPIX] | wT[576*64]
//   Tier B (ws >= 11.2 MB):                   om2[27*NPIX] | wT[576*64]  (NCHW direct gather)
// om2 is PLANE-MAJOR: om2[o*NPIX + p]  (coalesced writes in offconv, coalesced reads in dcn setup)

// ---------------------------------------------------------------------------
// Kernel 0a: NCHW -> NHWC transpose of the input via LDS tiles.
// ---------------------------------------------------------------------------
__global__ __launch_bounds__(256) void k_transpose_nhwc(const float* __restrict__ in,
                                                        float* __restrict__ out) {
    __shared__ float tile[CIN][33]; // +1 pad: conflict-free transposed reads
    int blk = blockIdx.x;           // b*H*5 + y*5 + wc
    int wc  = blk % 5;
    int by  = blk / 5;
    int y   = by % H_;
    int b   = by / H_;
    int w0  = wc * 32;
    int t   = threadIdx.x;

    int wi = t & 31, ch = t >> 5;   // ch: 0..7
#pragma unroll
    for (int r = 0; r < 8; ++r) {
        int c = r * 8 + ch;
        tile[c][wi] = in[((b * CIN + c) * H_ + y) * W_ + w0 + wi]; // coalesced in w
    }
    __syncthreads();
    int c2 = t & 63, wj = t >> 6;   // wj: 0..3
#pragma unroll
    for (int r = 0; r < 8; ++r) {
        int wi2 = r * 4 + wj;
        out[((b * H_ + y) * W_ + w0 + wi2) * CIN + c2] = tile[c2][wi2]; // coalesced in c
    }
}

// ---------------------------------------------------------------------------
// Kernel 0b: w_dcn (Cout,Cin,3,3) -> wT[(k*64 + c)*64 + co]
// ---------------------------------------------------------------------------
__global__ void k_transpose_w(const float* __restrict__ w, float* __restrict__ wT) {
    int i  = blockIdx.x * 256 + threadIdx.x;
    int co = i & 63;
    int kc = i >> 6;
    int c  = kc & 63;
    int k  = kc >> 6;
    wT[i] = w[(co * CIN + c) * 9 + k];
}

// ---------------------------------------------------------------------------
// Kernel A v2: offset conv, 3 output-groups of 9 channels.
// R7 counters showed v1 at 240us: VGPR=32 (27 accs spilled to scratch) and
// 400 blocks = 1.56 blocks/CU (occupancy 18%, latency-exposed). v2: grid
// 1200 blocks (3 groups x 400 pixel-blocks), 9 accumulators/thread (~50
// VGPR, no spill), launch_bounds(256,4) caps VGPR at 128. Input re-read 3x
// (L3-resident, 26 MB). Swizzle: XCD chunk = 150 consecutive ids; trio
// {3pb,3pb+1,3pb+2} (same pixels, 3 groups) lands on one XCD -> L2 reuse.
// Output om2 plane-major -> 9 fully-coalesced 256B stores.
// ---------------------------------------------------------------------------
__global__ __launch_bounds__(256, 4) void k_offconv(const float* __restrict__ in,
                                                    const float* __restrict__ wo,
                                                    const float* __restrict__ bo,
                                                    float* __restrict__ om2) {
    int bid = (int)blockIdx.x;                 // 0..1199
    int id  = (bid & 7) * 150 + (bid >> 3);    // XCD swizzle (1200 = 8*150, bijective)
    int g   = id % 3;                          // output group: o in [g*9, g*9+9)
    int pb  = id / 3;                          // pixel block 0..399
    int p   = pb * 256 + threadIdx.x;          // 0..NPIX-1
    int b   = p / HW_;
    int rem = p - b * HW_;
    int y   = rem / W_;
    int x   = rem - y * W_;

    // c-invariant per-tap offsets + validity (clamped -> branch-free loads)
    int   off[9];
    float valid[9];
#pragma unroll
    for (int di = 0; di < 3; ++di) {
        int yy = y + di - 1;
        int yc = min(max(yy, 0), H_ - 1);
        bool yok = (yy >= 0) & (yy < H_);
#pragma unroll
        for (int dj = 0; dj < 3; ++dj) {
            int xx = x + dj - 1;
            int xc = min(max(xx, 0), W_ - 1);
            bool ok = yok & (xx >= 0) & (xx < W_);
            off[di * 3 + dj]   = yc * W_ + xc;
            valid[di * 3 + dj] = ok ? 1.f : 0.f;
        }
    }

    float acc[9];
#pragma unroll
    for (int j = 0; j < 9; ++j) acc[j] = bo[g * 9 + j];

    const float* inb = in + (size_t)b * CIN * HW_;
    const float* wg  = wo + (size_t)(g * 9) * 576;   // scalar base (g uniform per block)
#pragma unroll 2
    for (int c = 0; c < CIN; ++c) {
        float v[9];
#pragma unroll
        for (int tp = 0; tp < 9; ++tp)
            v[tp] = inb[c * HW_ + off[tp]] * valid[tp];   // coalesced in x
#pragma unroll
        for (int j = 0; j < 9; ++j) {
#pragma unroll
            for (int tp = 0; tp < 9; ++tp)
                acc[j] += v[tp] * wg[j * 576 + c * 9 + tp]; // uniform addr -> s_load
        }
    }
#pragma unroll
    for (int j = 0; j < 9; ++j)
        om2[(size_t)(g * 9 + j) * NPIX + p] = acc[j];       // coalesced 256B stores
}

// ---------------------------------------------------------------------------
// Kernel B: deformable sampling + K-chunked register-tiled GEMM.
// Block = 256 threads (4 waves), TILE_P=128 contiguous pixels, all 64 couts.
// Template NHWC: true  -> float2-per-lane gathers from x_nhwc (Tier A)
//                false -> scalar NCHW direct gathers (Tier B fallback).
// Per tap k:
//   setup: threads t<128 read om2 plane-major (coalesced), build sk[pix][8].
//   stage: vals[c][pix]: NHWC path loads float2 (c-pair) per lane -> half
//          the VMEM instrs of R7; writes two b32 (LDS 4-way, measured minor).
//   compute: wave w owns couts [16w,16w+16) (uniform -> s_load weights).
//          Thread = 2 pix x 16 couts, 32 acc: 1 ds_read_b64 + 32 FMA per c.
// LDS 37.3 KB; launch_bounds(256,4): VGPR 52 measured, 4 blocks/CU by LDS.
// Epilogue: transpose via vals -> 256B-coalesced NCHW stores.
// ---------------------------------------------------------------------------
template <bool NHWC>
__global__ __launch_bounds__(256, 4) void k_dcn(const float* __restrict__ xsrc,
                                                const float* __restrict__ om2,
                                                const float* __restrict__ wT,
                                                const float* __restrict__ bd,
                                                float* __restrict__ out) {
    __shared__ __align__(16) float sk[TILE_P * 8];        //  4,096 B per-tap setup
    __shared__ __align__(16) float vals[64 * VPITCH];     // 33,280 B (reused as outs)

    int t   = threadIdx.x;
    int bid = (int)blockIdx.x;
    int blk = (bid & 7) * ((NPIX / TILE_P) / 8) + (bid >> 3); // XCD swizzle (800%8==0)
    int p0  = blk * TILE_P;
    int b   = p0 / HW_;          // uniform per block (128 | 25600)
    int rb  = p0 - b * HW_;

    int lane = t & 63;
    int co0  = __builtin_amdgcn_readfirstlane((t >> 6) << 4); // wave-uniform cout base

    float acc[2][16];
#pragma unroll
    for (int j = 0; j < 16; ++j) {
        float bj = bd[co0 + j];
        acc[0][j] = bj;
        acc[1][j] = bj;
    }

    const float* base = xsrc + (size_t)b * CIN * HW_;

    for (int k = 0; k < 9; ++k) {
        __syncthreads(); // prev compute done reading vals; sk free to rewrite

        // ---- per-tap setup (threads 0..127, one pixel each) --------------
        if (t < TILE_P) {
            int pix = t;
            int p   = p0 + pix;
            int rem = rb + pix;
            int y   = rem / W_;
            int x   = rem - y * W_;
            float oy = om2[(size_t)(2 * k) * NPIX + p];      // coalesced (plane-major)
            float ox = om2[(size_t)(2 * k + 1) * NPIX + p];
            float mr = om2[(size_t)(18 + k) * NPIX + p];
            float m  = 1.f / (1.f + expf(-mr));
            int ki = k / 3, kj = k - ki * 3;
            float fy  = (float)(y - 1 + ki) + oy;
            float fx  = (float)(x - 1 + kj) + ox;
            float fy0 = floorf(fy), fx0 = floorf(fx);
            float dy = fy - fy0, dx = fx - fx0;
            int iy = (int)fy0, ix = (int)fx0;
            bool yok0 = (iy >= 0) & (iy < H_);
            bool yok1 = (iy + 1 >= 0) & (iy + 1 < H_);
            bool xok0 = (ix >= 0) & (ix < W_);
            bool xok1 = (ix + 1 >= 0) & (ix + 1 < W_);
            int iyc0 = min(max(iy, 0), H_ - 1);
            int iyc1 = min(max(iy + 1, 0), H_ - 1);
            int ixc0 = min(max(ix, 0), W_ - 1);
            int ixc1 = min(max(ix + 1, 0), W_ - 1);
            const int mul = NHWC ? 64 : 1;
            float4 swt, sof;
            swt.x = (1.f - dy) * (1.f - dx) * m * (float)(yok0 & xok0);
            swt.y = (1.f - dy) * dx         * m * (float)(yok0 & xok1);
            swt.z = dy * (1.f - dx)         * m * (float)(yok1 & xok0);
            swt.w = dy * dx                 * m * (float)(yok1 & xok1);
            sof.x = __int_as_float((iyc0 * W_ + ixc0) * mul);
            sof.y = __int_as_float((iyc0 * W_ + ixc1) * mul);
            sof.z = __int_as_float((iyc1 * W_ + ixc0) * mul);
            sof.w = __int_as_float((iyc1 * W_ + ixc1) * mul);
            *reinterpret_cast<float4*>(sk + pix * 8)     = swt;
            *reinterpret_cast<float4*>(sk + pix * 8 + 4) = sof;
        }
        __syncthreads(); // sk ready

        // ---- stage vals[c][pix] (branch-free gathers) --------------------
        if constexpr (NHWC) {
            // float2 per lane: (c-pair, pix); 16 iters, half the VMEM instrs.
#pragma unroll 4
            for (int it = 0; it < 16; ++it) {
                int i     = t + it * 256;          // 0..4095
                int cpair = i & 31;
                int c0    = cpair * 2;             // even -> 8B-aligned (rows 256B-aligned)
                int pix   = i >> 5;                // 0..127
                const float* s = sk + pix * 8;
                float4 sw = *reinterpret_cast<const float4*>(s);
                float4 so = *reinterpret_cast<const float4*>(s + 4);
                float2 g00 = *reinterpret_cast<const float2*>(base + __float_as_int(so.x) + c0);
                float2 g01 = *reinterpret_cast<const float2*>(base + __float_as_int(so.y) + c0);
                float2 g10 = *reinterpret_cast<const float2*>(base + __float_as_int(so.z) + c0);
                float2 g11 = *reinterpret_cast<const float2*>(base + __float_as_int(so.w) + c0);
                vals[c0 * VPITCH + pix]       = g00.x * sw.x + g01.x * sw.y + g10.x * sw.z + g11.x * sw.w;
                vals[(c0 + 1) * VPITCH + pix] = g00.y * sw.x + g01.y * sw.y + g10.y * sw.z + g11.y * sw.w;
            }
        } else {
            int cbase = (t & 63) * HW_;
#pragma unroll 4
            for (int it = 0; it < 32; ++it) {
                int i   = t + it * 256;
                int c   = i & 63;
                int pix = i >> 6;
                const float* s = sk + pix * 8;
                float4 sw = *reinterpret_cast<const float4*>(s);
                float4 so = *reinterpret_cast<const float4*>(s + 4);
                float g00 = base[__float_as_int(so.x) + cbase];
                float g01 = base[__float_as_int(so.y) + cbase];
                float g10 = base[__float_as_int(so.z) + cbase];
                float g11 = base[__float_as_int(so.w) + cbase];
                vals[c * VPITCH + pix] = g00 * sw.x + g01 * sw.y + g10 * sw.z + g11 * sw.w;
            }
        }
        __syncthreads(); // vals ready

        // ---- compute: 64 c-steps, 2 pix x 16 couts per thread ------------
        const float* wk = wT + (k * 64) * 64 + co0;
#pragma unroll 4
        for (int c = 0; c < 64; ++c) {
            float2 v = *reinterpret_cast<const float2*>(vals + c * VPITCH + 2 * lane);
            const float* wp = wk + c * 64;   // wave-uniform address -> s_load
            float4 wv0 = *reinterpret_cast<const float4*>(wp);
            float4 wv1 = *reinterpret_cast<const float4*>(wp + 4);
            float4 wv2 = *reinterpret_cast<const float4*>(wp + 8);
            float4 wv3 = *reinterpret_cast<const float4*>(wp + 12);
            float wr[16] = {wv0.x, wv0.y, wv0.z, wv0.w,
                            wv1.x, wv1.y, wv1.z, wv1.w,
                            wv2.x, wv2.y, wv2.z, wv2.w,
                            wv3.x, wv3.y, wv3.z, wv3.w};
#pragma unroll
            for (int j = 0; j < 16; ++j) {
                acc[0][j] += v.x * wr[j];
                acc[1][j] += v.y * wr[j];
            }
        }
    }

    // ---- Epilogue: transpose via LDS -> coalesced NCHW stores ------------
    __syncthreads(); // all compute reads of vals done
#pragma unroll
    for (int j = 0; j < 16; ++j) {
        float2 o2;
        o2.x = acc[0][j];
        o2.y = acc[1][j];
        *reinterpret_cast<float2*>(vals + (co0 + j) * VPITCH + 2 * lane) = o2;
    }
    __syncthreads();
#pragma unroll 4
    for (int it = 0; it < 32; ++it) {
        int i   = t + it * 256;
        int co  = i >> 7;            // 0..63
        int pix = i & 127;           // 64 consecutive per wave-instr -> 256B stores
        out[((size_t)(b * COUT + co)) * HW_ + rb + pix] = vals[co * VPITCH + pix];
    }
}

extern "C" void kernel_launch(void* const* d_in, const int* in_sizes, int n_in,
                              void* d_out, int out_size, void* d_ws, size_t ws_size,
                              hipStream_t stream) {
    const float* input = (const float*)d_in[0]; // (4,64,160,160)
    const float* w_off = (const float*)d_in[1]; // (27,64,3,3)
    const float* b_off = (const float*)d_in[2]; // (27,)
    const float* w_dcn = (const float*)d_in[3]; // (64,64,3,3)
    const float* b_dcn = (const float*)d_in[4]; // (64,)
    float* out = (float*)d_out;                 // (4,64,160,160)

    const size_t XN_F = (size_t)NPIX * CIN;     // 6,553,600 floats
    const size_t OM_F = (size_t)NPIX * OFFC;    // 2,764,800 floats
    const size_t WT_F = 576 * 64;               //    36,864 floats
    const size_t need_full = (XN_F + OM_F + WT_F) * sizeof(float); // ~37.4 MB

    float* ws = (float*)d_ws;
    // ws_size is constant across calls -> branch is graph-capture-safe.
    if (ws_size >= need_full) {
        // Tier A: full pipeline with NHWC-staged input. (R7 ran this tier.)
        float* x_nhwc = ws;
        float* om2    = ws + XN_F;
        float* wT     = om2 + OM_F;
        k_transpose_nhwc<<<dim3(B_ * H_ * 5), dim3(256), 0, stream>>>(input, x_nhwc);
        k_transpose_w<<<dim3(144), dim3(256), 0, stream>>>(w_dcn, wT);
        k_offconv<<<dim3(1200), dim3(256), 0, stream>>>(input, w_off, b_off, om2);
        k_dcn<true><<<dim3(NPIX / TILE_P), dim3(256), 0, stream>>>(x_nhwc, om2, wT, b_dcn, out);
    } else {
        // Tier B: no NHWC staging; k_dcn gathers NCHW directly (slower, safe).
        float* om2 = ws;
        float* wT  = om2 + OM_F;
        k_transpose_w<<<dim3(144), dim3(256), 0, stream>>>(w_dcn, wT);
        k_offconv<<<dim3(1200), dim3(256), 0, stream>>>(input, w_off, b_off, om2);
        k_dcn<false><<<dim3(NPIX / TILE_P), dim3(256), 0, stream>>>(input, om2, wT, b_dcn, out);
    }
}

// Round 13
// 319.947 us; speedup vs baseline: 1.3808x; 1.0264x over previous
//
#include <hip/hip_runtime.h>
#include <math.h>

// Problem constants: B=4, Cin=64, H=W=160, K=3, pad=1, stride=1, Cout=64
#define B_   4
#define CIN  64
#define H_   160
#define W_   160
#define COUT 64
#define OFFC 27            // 27 offset-conv output channels
#define HW_  (H_ * W_)     // 25600
#define NPIX (B_ * HW_)    // 102400

#define TILE_P 64          // pixels per k_dcn block (64 | HW_) -- R8: 128 gave occ 24.6%
#define VP2    65          // vals pitch: odd -> all LDS phases 2-way (free)

// Workspace (floats):
//   Tier A (ws >= 37.4 MB): x_nhwc[NPIX*64] | om2[27*NPIX] | wT[576*64]
//   Tier B (ws >= 11.2 MB):                   om2[27*NPIX] | wT[576*64]
// om2 PLANE-MAJOR: om2[o*NPIX + p]

// ---------------------------------------------------------------------------
// Kernel 0a: NCHW -> NHWC transpose of the input via LDS tiles.
// ---------------------------------------------------------------------------
__global__ __launch_bounds__(256) void k_transpose_nhwc(const float* __restrict__ in,
                                                        float* __restrict__ out) {
    __shared__ float tile[CIN][33];
    int blk = blockIdx.x;           // b*H*5 + y*5 + wc
    int wc  = blk % 5;
    int by  = blk / 5;
    int y   = by % H_;
    int b   = by / H_;
    int w0  = wc * 32;
    int t   = threadIdx.x;

    int wi = t & 31, ch = t >> 5;
#pragma unroll
    for (int r = 0; r < 8; ++r) {
        int c = r * 8 + ch;
        tile[c][wi] = in[((b * CIN + c) * H_ + y) * W_ + w0 + wi];
    }
    __syncthreads();
    int c2 = t & 63, wj = t >> 6;
#pragma unroll
    for (int r = 0; r < 8; ++r) {
        int wi2 = r * 4 + wj;
        out[((b * H_ + y) * W_ + w0 + wi2) * CIN + c2] = tile[c2][wi2];
    }
}

// ---------------------------------------------------------------------------
// Kernel 0b: w_dcn (Cout,Cin,3,3) -> wT[(k*64 + c)*64 + co]
// ---------------------------------------------------------------------------
__global__ void k_transpose_w(const float* __restrict__ w, float* __restrict__ wT) {
    int i  = blockIdx.x * 256 + threadIdx.x;
    int co = i & 63;
    int kc = i >> 6;
    int c  = kc & 63;
    int k  = kc >> 6;
    wT[i] = w[(co * CIN + c) * 9 + k];
}

// ---------------------------------------------------------------------------
// Kernel A v3: offset conv, 3 groups of 9 outs. v2 timeline-est ~115us.
// Change: interleave TWO c-planes (18 independent loads in flight before
// 162 FMAs) -- v1 measured VALUBusy 27% (latency-bound); this doubles
// per-wave outstanding loads. ~60 VGPR, no spill (LB(256,4) cap 128).
// ---------------------------------------------------------------------------
__global__ __launch_bounds__(256, 4) void k_offconv(const float* __restrict__ in,
                                                    const float* __restrict__ wo,
                                                    const float* __restrict__ bo,
                                                    float* __restrict__ om2) {
    int bid = (int)blockIdx.x;                 // 0..1199
    int id  = (bid & 7) * 150 + (bid >> 3);    // XCD swizzle (1200 = 8*150)
    int g   = id % 3;                          // output group
    int pb  = id / 3;                          // pixel block 0..399
    int p   = pb * 256 + threadIdx.x;
    int b   = p / HW_;
    int rem = p - b * HW_;
    int y   = rem / W_;
    int x   = rem - y * W_;

    int   off[9];
    float valid[9];
#pragma unroll
    for (int di = 0; di < 3; ++di) {
        int yy = y + di - 1;
        int yc = min(max(yy, 0), H_ - 1);
        bool yok = (yy >= 0) & (yy < H_);
#pragma unroll
        for (int dj = 0; dj < 3; ++dj) {
            int xx = x + dj - 1;
            int xc = min(max(xx, 0), W_ - 1);
            bool ok = yok & (xx >= 0) & (xx < W_);
            off[di * 3 + dj]   = yc * W_ + xc;
            valid[di * 3 + dj] = ok ? 1.f : 0.f;
        }
    }

    float acc[9];
#pragma unroll
    for (int j = 0; j < 9; ++j) acc[j] = bo[g * 9 + j];

    const float* inb = in + (size_t)b * CIN * HW_;
    const float* wg  = wo + (size_t)(g * 9) * 576;
    for (int c = 0; c < CIN; c += 2) {
        float va[9], vb[9];
#pragma unroll
        for (int tp = 0; tp < 9; ++tp)
            va[tp] = inb[c * HW_ + off[tp]] * valid[tp];
#pragma unroll
        for (int tp = 0; tp < 9; ++tp)
            vb[tp] = inb[(c + 1) * HW_ + off[tp]] * valid[tp];
#pragma unroll
        for (int j = 0; j < 9; ++j) {
#pragma unroll
            for (int tp = 0; tp < 9; ++tp)
                acc[j] += va[tp] * wg[j * 576 + c * 9 + tp];
#pragma unroll
            for (int tp = 0; tp < 9; ++tp)
                acc[j] += vb[tp] * wg[j * 576 + (c + 1) * 9 + tp];
        }
    }
#pragma unroll
    for (int j = 0; j < 9; ++j)
        om2[(size_t)(g * 9 + j) * NPIX + p] = acc[j];       // coalesced
}

// ---------------------------------------------------------------------------
// Kernel B v3: deformable sampling + GEMM. R8 diagnosis: occ 24.6% (2.5
// blk/CU, 37.4KB LDS), VALUBusy 40%, conflicts 5.76M -> latency/barrier-
// bound. v3: TILE_P=64, LDS 18.6KB, grid 1600 (6.25 blk/CU), thread =
// 1 pix x 16 couts (acc[16], ~45 VGPR, LB(256,6) caps 85).
// VP2=65 (odd): stage write (c+pix)%32, compute read (c+lane)%32,
// transpose (co+lane)%32 -- ALL 2-way = free.
// ---------------------------------------------------------------------------
template <bool NHWC>
__global__ __launch_bounds__(256, 6) void k_dcn(const float* __restrict__ xsrc,
                                                const float* __restrict__ om2,
                                                const float* __restrict__ wT,
                                                const float* __restrict__ bd,
                                                float* __restrict__ out) {
    __shared__ __align__(16) float sk[TILE_P * 8];     //  2,048 B
    __shared__ __align__(16) float vals[64 * VP2];     // 16,640 B (reused as outs)

    int t   = threadIdx.x;
    int bid = (int)blockIdx.x;
    int blk = (bid & 7) * ((NPIX / TILE_P) / 8) + (bid >> 3); // 1600 = 8*200
    int p0  = blk * TILE_P;
    int b   = p0 / HW_;          // uniform per block (64 | 25600)
    int rb  = p0 - b * HW_;

    int lane = t & 63;
    int co0  = __builtin_amdgcn_readfirstlane((t >> 6) << 4); // wave-uniform cout base

    float acc[16];
#pragma unroll
    for (int j = 0; j < 16; ++j) acc[j] = bd[co0 + j];

    const float* base = xsrc + (size_t)b * CIN * HW_;

    for (int k = 0; k < 9; ++k) {
        __syncthreads(); // prev compute done reading vals

        // ---- per-tap setup (threads 0..63, one pixel each) ---------------
        if (t < TILE_P) {
            int p   = p0 + t;
            int rem = rb + t;
            int y   = rem / W_;
            int x   = rem - y * W_;
            float oy = om2[(size_t)(2 * k) * NPIX + p];      // coalesced
            float ox = om2[(size_t)(2 * k + 1) * NPIX + p];
            float mr = om2[(size_t)(18 + k) * NPIX + p];
            float m  = 1.f / (1.f + expf(-mr));
            int ki = k / 3, kj = k - ki * 3;
            float fy  = (float)(y - 1 + ki) + oy;
            float fx  = (float)(x - 1 + kj) + ox;
            float fy0 = floorf(fy), fx0 = floorf(fx);
            float dy = fy - fy0, dx = fx - fx0;
            int iy = (int)fy0, ix = (int)fx0;
            bool yok0 = (iy >= 0) & (iy < H_);
            bool yok1 = (iy + 1 >= 0) & (iy + 1 < H_);
            bool xok0 = (ix >= 0) & (ix < W_);
            bool xok1 = (ix + 1 >= 0) & (ix + 1 < W_);
            int iyc0 = min(max(iy, 0), H_ - 1);
            int iyc1 = min(max(iy + 1, 0), H_ - 1);
            int ixc0 = min(max(ix, 0), W_ - 1);
            int ixc1 = min(max(ix + 1, 0), W_ - 1);
            const int mul = NHWC ? 64 : 1;
            float4 swt, sof;
            swt.x = (1.f - dy) * (1.f - dx) * m * (float)(yok0 & xok0);
            swt.y = (1.f - dy) * dx         * m * (float)(yok0 & xok1);
            swt.z = dy * (1.f - dx)         * m * (float)(yok1 & xok0);
            swt.w = dy * dx                 * m * (float)(yok1 & xok1);
            sof.x = __int_as_float((iyc0 * W_ + ixc0) * mul);
            sof.y = __int_as_float((iyc0 * W_ + ixc1) * mul);
            sof.z = __int_as_float((iyc1 * W_ + ixc0) * mul);
            sof.w = __int_as_float((iyc1 * W_ + ixc1) * mul);
            *reinterpret_cast<float4*>(sk + t * 8)     = swt;
            *reinterpret_cast<float4*>(sk + t * 8 + 4) = sof;
        }
        __syncthreads(); // sk ready

        // ---- stage vals[c][pix]: lanes = 64 c of one pixel ---------------
        {
            int c     = lane;                        // per-lane channel
            int cterm = NHWC ? c : c * HW_;
#pragma unroll 4
            for (int it = 0; it < 16; ++it) {
                int pix = (t >> 6) + 4 * it;         // wave-uniform, covers 0..63
                const float* s = sk + pix * 8;
                float4 sw = *reinterpret_cast<const float4*>(s);
                float4 so = *reinterpret_cast<const float4*>(s + 4);
                float g00 = base[__float_as_int(so.x) + cterm];
                float g01 = base[__float_as_int(so.y) + cterm];
                float g10 = base[__float_as_int(so.z) + cterm];
                float g11 = base[__float_as_int(so.w) + cterm];
                vals[c * VP2 + pix] = g00 * sw.x + g01 * sw.y + g10 * sw.z + g11 * sw.w;
            }
        }
        __syncthreads(); // vals ready

        // ---- compute: 64 c-steps, 1 pix x 16 couts per thread ------------
        const float* wk = wT + (k * 64) * 64 + co0;
#pragma unroll 4
        for (int c = 0; c < 64; ++c) {
            float v = vals[c * VP2 + lane];          // 2-way (free)
            const float* wp = wk + c * 64;           // wave-uniform -> s_load
            float4 wv0 = *reinterpret_cast<const float4*>(wp);
            float4 wv1 = *reinterpret_cast<const float4*>(wp + 4);
            float4 wv2 = *reinterpret_cast<const float4*>(wp + 8);
            float4 wv3 = *reinterpret_cast<const float4*>(wp + 12);
            acc[0]  += v * wv0.x;  acc[1]  += v * wv0.y;
            acc[2]  += v * wv0.z;  acc[3]  += v * wv0.w;
            acc[4]  += v * wv1.x;  acc[5]  += v * wv1.y;
            acc[6]  += v * wv1.z;  acc[7]  += v * wv1.w;
            acc[8]  += v * wv2.x;  acc[9]  += v * wv2.y;
            acc[10] += v * wv2.z;  acc[11] += v * wv2.w;
            acc[12] += v * wv3.x;  acc[13] += v * wv3.y;
            acc[14] += v * wv3.z;  acc[15] += v * wv3.w;
        }
    }

    // ---- Epilogue: transpose via LDS -> coalesced NCHW stores ------------
    __syncthreads();
#pragma unroll
    for (int j = 0; j < 16; ++j)
        vals[(co0 + j) * VP2 + lane] = acc[j];       // 2-way (free)
    __syncthreads();
#pragma unroll 4
    for (int it = 0; it < 16; ++it) {
        int i  = t + it * 256;
        int co = i >> 6;             // wave-uniform per iter
        int px = i & 63;             // 64 consecutive -> 256B stores
        out[((size_t)(b * COUT + co)) * HW_ + rb + px] = vals[co * VP2 + px];
    }
}

extern "C" void kernel_launch(void* const* d_in, const int* in_sizes, int n_in,
                              void* d_out, int out_size, void* d_ws, size_t ws_size,
                              hipStream_t stream) {
    const float* input = (const float*)d_in[0]; // (4,64,160,160)
    const float* w_off = (const float*)d_in[1]; // (27,64,3,3)
    const float* b_off = (const float*)d_in[2]; // (27,)
    const float* w_dcn = (const float*)d_in[3]; // (64,64,3,3)
    const float* b_dcn = (const float*)d_in[4]; // (64,)
    float* out = (float*)d_out;                 // (4,64,160,160)

    const size_t XN_F = (size_t)NPIX * CIN;
    const size_t OM_F = (size_t)NPIX * OFFC;
    const size_t WT_F = 576 * 64;
    const size_t need_full = (XN_F + OM_F + WT_F) * sizeof(float);

    float* ws = (float*)d_ws;
    if (ws_size >= need_full) {
        float* x_nhwc = ws;
        float* om2    = ws + XN_F;
        float* wT     = om2 + OM_F;
        k_transpose_nhwc<<<dim3(B_ * H_ * 5), dim3(256), 0, stream>>>(input, x_nhwc);
        k_transpose_w<<<dim3(144), dim3(256), 0, stream>>>(w_dcn, wT);
        k_offconv<<<dim3(1200), dim3(256), 0, stream>>>(input, w_off, b_off, om2);
        k_dcn<true><<<dim3(NPIX / TILE_P), dim3(256), 0, stream>>>(x_nhwc, om2, wT, b_dcn, out);
    } else {
        float* om2 = ws;
        float* wT  = om2 + OM_F;
        k_transpose_w<<<dim3(144), dim3(256), 0, stream>>>(w_dcn, wT);
        k_offconv<<<dim3(1200), dim3(256), 0, stream>>>(input, w_off, b_off, om2);
        k_dcn<false><<<dim3(NPIX / TILE_P), dim3(256), 0, stream>>>(input, om2, wT, b_dcn, out);
    }
}